// Round 3
// baseline (70.287 us; speedup 1.0000x reference)
//
#include <hip/hip_runtime.h>
#include <hip/hip_bf16.h>

#define NN 2048
#define FIN 512
#define FOUT 128
#define NEGV -9e15f
#define ALPHAV 0.2f

typedef __attribute__((ext_vector_type(8))) short bf16x8;
typedef __attribute__((ext_vector_type(4))) float f32x4;

__device__ __forceinline__ unsigned cvt_pk_bf16(float lo, float hi) {
    unsigned r;
    asm("v_cvt_pk_bf16_f32 %0, %1, %2" : "=v"(r) : "v"(lo), "v"(hi));
    return r;   // low16 = bf16(lo), high16 = bf16(hi), RNE
}

__device__ __forceinline__ unsigned short f32_to_bf16(float f) {
    unsigned int u = __float_as_uint(f);
    unsigned int r = (u + 0x7FFFu + ((u >> 16) & 1u)) >> 16;   // RNE
    return (unsigned short)r;
}

// ---------------- Kernel W: repack W -> bf16 hi/lo MFMA-B fragments ----------------
// grid = 16 kt x 8 t_o = 128 blocks, 64 threads.
// whi[(kt*8+t_o)*512 + l*8 + jj] = bf16_hi( W[kt*32+(l>>4)*8+jj][t_o*16+(l&15)] )
__global__ void k_wrep(const float* __restrict__ W,
                       unsigned short* __restrict__ whi,
                       unsigned short* __restrict__ wlo) {
    int kt = blockIdx.x >> 3;
    int t_o = blockIdx.x & 7;
    int l = threadIdx.x;
    int lr = l & 15, lg = l >> 4;
    unsigned short vh[8], vl[8];
#pragma unroll
    for (int jj = 0; jj < 8; jj++) {
        float f = W[(size_t)(kt * 32 + lg * 8 + jj) * FOUT + t_o * 16 + lr];
        unsigned short h = f32_to_bf16(f);
        float hf = __uint_as_float(((unsigned)h) << 16);
        vh[jj] = h;
        vl[jj] = f32_to_bf16(f - hf);
    }
    size_t o = ((size_t)(kt * 8 + t_o) * 64 + l) * 8;
    *(uint4*)(whi + o) = *(const uint4*)vh;
    *(uint4*)(wlo + o) = *(const uint4*)vl;
}

// ---------------- Kernel H: h = x@W via split-bf16 MFMA; t1/t2; frag repack ----------------
// grid = 8192/64 = 128 blocks, 256 threads (4 waves). Wave wv owns rows blk*64+wv*16..+15, all 128 cols.
__global__ void __launch_bounds__(256) k_h(const float* __restrict__ x,
                                           const unsigned short* __restrict__ whi,
                                           const unsigned short* __restrict__ wlo,
                                           const float* __restrict__ a1,
                                           const float* __restrict__ a2,
                                           unsigned short* __restrict__ hb,
                                           float* __restrict__ t1,
                                           float* __restrict__ t2) {
    __shared__ unsigned short ldst[4][128][24];   // [wave][col][row-local], 24 KB, 16B-aligned rows
    int blk = blockIdx.x;
    int tid = threadIdx.x;
    int wv = tid >> 6, l = tid & 63;
    int lr = l & 15, lg = l >> 4;
    int row0 = blk * 64 + wv * 16;

    const float* xp = x + (size_t)(row0 + lr) * FIN + lg * 8;

    f32x4 acc[8];
#pragma unroll
    for (int t = 0; t < 8; t++) acc[t] = (f32x4){0.f, 0.f, 0.f, 0.f};

    for (int kt = 0; kt < FIN / 32; kt++) {
        float4 xa = *(const float4*)(xp + kt * 32);
        float4 xb = *(const float4*)(xp + kt * 32 + 4);
        float f[8] = {xa.x, xa.y, xa.z, xa.w, xb.x, xb.y, xb.z, xb.w};
        unsigned uh[4], ul[4];
#pragma unroll
        for (int w = 0; w < 4; w++) {
            uh[w] = cvt_pk_bf16(f[2 * w], f[2 * w + 1]);
            float r0 = f[2 * w]     - __uint_as_float(uh[w] << 16);
            float r1 = f[2 * w + 1] - __uint_as_float(uh[w] & 0xffff0000u);
            ul[w] = cvt_pk_bf16(r0, r1);
        }
        bf16x8 xh = *(const bf16x8*)uh;
        bf16x8 xl = *(const bf16x8*)ul;
        const unsigned short* wb = whi + (size_t)kt * 8 * 512 + l * 8;
        const unsigned short* lb = wlo + (size_t)kt * 8 * 512 + l * 8;
#pragma unroll
        for (int t = 0; t < 8; t++) {
            bf16x8 wh = *(const bf16x8*)(wb + t * 512);
            bf16x8 wl = *(const bf16x8*)(lb + t * 512);
            acc[t] = __builtin_amdgcn_mfma_f32_16x16x32_bf16(xh, wh, acc[t], 0, 0, 0);
            acc[t] = __builtin_amdgcn_mfma_f32_16x16x32_bf16(xl, wh, acc[t], 0, 0, 0);
            acc[t] = __builtin_amdgcn_mfma_f32_16x16x32_bf16(xh, wl, acc[t], 0, 0, 0);
        }
    }

    // t1/t2: row = lg*4+r spread across 16 lanes (lr) x 8 cols each
    {
        float p1[4] = {0.f, 0.f, 0.f, 0.f}, p2[4] = {0.f, 0.f, 0.f, 0.f};
#pragma unroll
        for (int t = 0; t < 8; t++) {
            float a1v = a1[t * 16 + lr];
            float a2v = a2[t * 16 + lr];
#pragma unroll
            for (int r = 0; r < 4; r++) {
                p1[r] = fmaf(acc[t][r], a1v, p1[r]);
                p2[r] = fmaf(acc[t][r], a2v, p2[r]);
            }
        }
#pragma unroll
        for (int off = 1; off < 16; off <<= 1) {
#pragma unroll
            for (int r = 0; r < 4; r++) {
                p1[r] += __shfl_xor(p1[r], off);
                p2[r] += __shfl_xor(p2[r], off);
            }
        }
        if (lr == 0) {
#pragma unroll
            for (int r = 0; r < 4; r++) {
                t1[row0 + lg * 4 + r] = p1[r];
                t2[row0 + lg * 4 + r] = p2[r];
            }
        }
    }

    // stash bf16(h) transposed in LDS: ldst[wv][col][row-local]
#pragma unroll
    for (int t = 0; t < 8; t++) {
        unsigned u0 = cvt_pk_bf16(acc[t][0], acc[t][1]);
        unsigned u1 = cvt_pk_bf16(acc[t][2], acc[t][3]);
        uint2 u = {u0, u1};
        *(uint2*)&ldst[wv][t * 16 + lr][lg * 4] = u;
    }
    __syncthreads();

    // cooperative frag store: wave wv -> jt_loc = wv>>1 (32 j-rows), t_o = (wv&1)*4 .. +3
    // frag elem jj: j = lg*8+jj -> source wave region jt_loc*2 + (lg>>1), local row (lg&1)*8+jj
    {
        int jt_loc = wv >> 1;
        size_t jtg = (size_t)blk * 2 + jt_loc;
#pragma unroll
        for (int tt = 0; tt < 4; tt++) {
            int t_o = (wv & 1) * 4 + tt;
            uint4 v = *(const uint4*)&ldst[jt_loc * 2 + (lg >> 1)][t_o * 16 + lr][(lg & 1) * 8];
            *(uint4*)(hb + jtg * 4096 + t_o * 512 + l * 8) = v;
        }
    }
}

// ---------------- Kernel B: fused masked-softmax attention + PV (MFMA) ----------------
// grid = B*N/16 = 512 blocks, 256 threads (4 waves).
// All waves share the same 16 i-rows; wave wv processes j-tiles jt ≡ wv (mod 4),
// each wave owns all 8 o-tiles. Cross-wave flash combine in LDS at the end.
__global__ void __launch_bounds__(256) k_attn(const int* __restrict__ adj,
                                              const float* __restrict__ t1g,
                                              const float* __restrict__ t2g,
                                              const unsigned short* __restrict__ hb,
                                              const int* __restrict__ d1p,
                                              const int* __restrict__ d2p,
                                              float* __restrict__ out) {
    __shared__ float accbuf[4][16][132];    // 33792 B, 2-way-free padding
    __shared__ float lds_m[4][16];
    __shared__ float lds_s[4][16];
    __shared__ float lds_inv[16];

    int blk = blockIdx.x;
    int b = blk >> 7;
    int i0 = (blk & 127) * 16;
    int tid = threadIdx.x;
    int wv = tid >> 6;
    int l = tid & 63;
    int lr = l & 15, lg = l >> 4;
    int d1 = d1p[0], d2 = d2p[0];

    float t1v = t1g[b * NN + i0 + lr];
    const int* adjRow = adj + ((size_t)(b * NN + i0 + lr)) * NN + lg * 8;
    const float* t2p = t2g + b * NN + lg * 8;
    const unsigned short* hbbase = hb + (size_t)b * 64 * 4096 + (size_t)l * 8;

    float m = NEGV, s = 0.f;
    f32x4 acc[8];
#pragma unroll
    for (int t = 0; t < 8; t++) acc[t] = (f32x4){0.f, 0.f, 0.f, 0.f};

#pragma unroll 2
    for (int jt = wv; jt < NN / 32; jt += 4) {
        int4 av0 = *(const int4*)(adjRow + jt * 32);
        int4 av1 = *(const int4*)(adjRow + jt * 32 + 4);
        float4 tb0 = *(const float4*)(t2p + jt * 32);
        float4 tb1 = *(const float4*)(t2p + jt * 32 + 4);
        bf16x8 hf[8];
#pragma unroll
        for (int t = 0; t < 8; t++)
            hf[t] = *(const bf16x8*)(hbbase + (size_t)jt * 4096 + t * 512);

        int ai[8] = {av0.x, av0.y, av0.z, av0.w, av1.x, av1.y, av1.z, av1.w};
        float tv[8] = {tb0.x, tb0.y, tb0.z, tb0.w, tb1.x, tb1.y, tb1.z, tb1.w};
        float att[8];
#pragma unroll
        for (int jj = 0; jj < 8; jj++) {
            float v = t1v + tv[jj];
            float e = fmaxf(v, ALPHAV * v);          // leaky relu (alpha<1)
            att[jj] = (ai[jj] == d1 || ai[jj] == d2) ? e : NEGV;
        }
        float mx = att[0];
#pragma unroll
        for (int jj = 1; jj < 8; jj++) mx = fmaxf(mx, att[jj]);
        mx = fmaxf(mx, __shfl_xor(mx, 16));
        mx = fmaxf(mx, __shfl_xor(mx, 32));

        if (__any(mx > m + 8.f)) {                   // T13 defer-max
            float mnew = fmaxf(m, mx);
            float scale = __expf(m - mnew);
            m = mnew;
            s *= scale;
            float scr[4];
#pragma unroll
            for (int r = 0; r < 4; r++) scr[r] = __shfl(scale, lg * 4 + r);
#pragma unroll
            for (int t = 0; t < 8; t++)
#pragma unroll
                for (int r = 0; r < 4; r++) acc[t][r] *= scr[r];
        }

        float p[8];
        float psum = 0.f;
#pragma unroll
        for (int jj = 0; jj < 8; jj++) {
            p[jj] = __expf(att[jj] - m);             // masked & m==NEGV -> exp(0)=1 (matches ref)
            psum += p[jj];
        }
        s += psum;

        unsigned u[4];
#pragma unroll
        for (int w = 0; w < 4; w++) u[w] = cvt_pk_bf16(p[2 * w], p[2 * w + 1]);
        bf16x8 pa = *(const bf16x8*)u;
#pragma unroll
        for (int t = 0; t < 8; t++)
            acc[t] = __builtin_amdgcn_mfma_f32_16x16x32_bf16(pa, hf[t], acc[t], 0, 0, 0);
    }

    // cross-wave flash combine
    s += __shfl_xor(s, 16);
    s += __shfl_xor(s, 32);
    if (l < 16) { lds_m[wv][lr] = m; lds_s[wv][lr] = s; }
    __syncthreads();

    float mt = fmaxf(fmaxf(lds_m[0][lr], lds_m[1][lr]),
                     fmaxf(lds_m[2][lr], lds_m[3][lr]));
    if (wv == 0 && l < 16) {
        float st = 0.f;
#pragma unroll
        for (int w = 0; w < 4; w++) st += lds_s[w][lr] * __expf(lds_m[w][lr] - mt);
        lds_inv[lr] = 1.0f / st;
    }
    float scale = __expf(m - mt);
    float scr[4];
#pragma unroll
    for (int r = 0; r < 4; r++) scr[r] = __shfl(scale, lg * 4 + r);
#pragma unroll
    for (int t = 0; t < 8; t++)
#pragma unroll
        for (int r = 0; r < 4; r++)
            accbuf[wv][lg * 4 + r][t * 16 + lr] = acc[t][r] * scr[r];
    __syncthreads();

#pragma unroll
    for (int e = 0; e < 8; e++) {
        int flat = tid + e * 256;
        int row = flat >> 7;
        int col = flat & 127;
        float sum = accbuf[0][row][col] + accbuf[1][row][col]
                  + accbuf[2][row][col] + accbuf[3][row][col];
        out[((size_t)b * NN + i0 + row) * FOUT + col] = sum * lds_inv[row];
    }
}

extern "C" void kernel_launch(void* const* d_in, const int* in_sizes, int n_in,
                              void* d_out, int out_size, void* d_ws, size_t ws_size,
                              hipStream_t stream) {
    const float* x  = (const float*)d_in[0];
    const float* W  = (const float*)d_in[1];
    const float* a1 = (const float*)d_in[2];
    const float* a2 = (const float*)d_in[3];
    const int* adj  = (const int*)d_in[4];
    // d_in[5] = adj_tree (unused by reference forward)
    const int* d1p  = (const int*)d_in[6];
    const int* d2p  = (const int*)d_in[7];
    float* out = (float*)d_out;

    char* ws = (char*)d_ws;
    unsigned short* hbuf = (unsigned short*)(ws);                       // 2 MB
    float* t1            = (float*)(ws + 2u * 1024 * 1024);             // 32 KB
    float* t2            = (float*)(ws + 2u * 1024 * 1024 + 32 * 1024); // 32 KB
    unsigned short* whi  = (unsigned short*)(ws + 2u * 1024 * 1024 + 64 * 1024);  // 128 KB
    unsigned short* wlo  = (unsigned short*)(ws + 2u * 1024 * 1024 + 192 * 1024); // 128 KB

    k_wrep<<<dim3(128), dim3(64), 0, stream>>>(W, whi, wlo);
    k_h<<<dim3(128), dim3(256), 0, stream>>>(x, whi, wlo, a1, a2, hbuf, t1, t2);
    k_attn<<<dim3(512), dim3(256), 0, stream>>>(adj, t1, t2, hbuf, d1p, d2p, out);
}

// Round 4
// 44.595 us; speedup vs baseline: 1.5761x; 1.5761x over previous
//
#include <hip/hip_runtime.h>
#include <hip/hip_bf16.h>

#define NN 2048
#define FIN 512
#define FOUT 128
#define NEGV -9e15f
#define ALPHAV 0.2f

typedef __attribute__((ext_vector_type(8))) short bf16x8;
typedef __attribute__((ext_vector_type(4))) float f32x4;

__device__ __forceinline__ unsigned cvt_pk_bf16(float lo, float hi) {
    unsigned r;
    asm("v_cvt_pk_bf16_f32 %0, %1, %2" : "=v"(r) : "v"(lo), "v"(hi));
    return r;   // low16 = bf16(lo), high16 = bf16(hi), RNE
}

__device__ __forceinline__ unsigned short f32_to_bf16(float f) {
    unsigned int u = __float_as_uint(f);
    unsigned int r = (u + 0x7FFFu + ((u >> 16) & 1u)) >> 16;   // RNE
    return (unsigned short)r;
}

// ---------------- Kernel W: repack W -> bf16 hi/lo MFMA-B fragments ----------------
// grid = 16 kt x 8 t_o = 128 blocks, 64 threads.
// whi[(kt*8+t_o)*512 + l*8 + jj] = bf16_hi( W[kt*32+(l>>4)*8+jj][t_o*16+(l&15)] )
__global__ void k_wrep(const float* __restrict__ W,
                       unsigned short* __restrict__ whi,
                       unsigned short* __restrict__ wlo) {
    int kt = blockIdx.x >> 3;
    int t_o = blockIdx.x & 7;
    int l = threadIdx.x;
    int lr = l & 15, lg = l >> 4;
    unsigned short vh[8], vl[8];
#pragma unroll
    for (int jj = 0; jj < 8; jj++) {
        float f = W[(size_t)(kt * 32 + lg * 8 + jj) * FOUT + t_o * 16 + lr];
        unsigned short h = f32_to_bf16(f);
        float hf = __uint_as_float(((unsigned)h) << 16);
        vh[jj] = h;
        vl[jj] = f32_to_bf16(f - hf);
    }
    size_t o = ((size_t)(kt * 8 + t_o) * 64 + l) * 8;
    *(uint4*)(whi + o) = *(const uint4*)vh;
    *(uint4*)(wlo + o) = *(const uint4*)vl;
}

// ---------------- Kernel H: h = x@W via split-bf16 MFMA; t1/t2; frag repack ----------------
// grid = 8192/16 = 512 blocks, 256 threads (4 waves).
// Block owns 16 rows x 128 cols; wave wv owns o-tiles {2wv, 2wv+1}.
__global__ void __launch_bounds__(256) k_h(const float* __restrict__ x,
                                           const unsigned short* __restrict__ whi,
                                           const unsigned short* __restrict__ wlo,
                                           const float* __restrict__ a1,
                                           const float* __restrict__ a2,
                                           unsigned short* __restrict__ hb,
                                           float* __restrict__ t1,
                                           float* __restrict__ t2) {
    __shared__ float lds_t1[4][16];
    __shared__ float lds_t2[4][16];
    int blk = blockIdx.x;
    int tid = threadIdx.x;
    int wv = tid >> 6, l = tid & 63;
    int lr = l & 15, lg = l >> 4;
    int row0 = blk * 16;

    const float* xp = x + (size_t)(row0 + lr) * FIN + lg * 8;
    const unsigned short* wb = whi + (size_t)(2 * wv) * 512 + l * 8;
    const unsigned short* lb = wlo + (size_t)(2 * wv) * 512 + l * 8;

    f32x4 acc0 = {0.f, 0.f, 0.f, 0.f};
    f32x4 acc1 = {0.f, 0.f, 0.f, 0.f};

#pragma unroll 2
    for (int kt = 0; kt < FIN / 32; kt++) {
        float4 xa = *(const float4*)(xp + kt * 32);
        float4 xb = *(const float4*)(xp + kt * 32 + 4);
        bf16x8 wh0 = *(const bf16x8*)(wb + (size_t)kt * 4096);
        bf16x8 wh1 = *(const bf16x8*)(wb + (size_t)kt * 4096 + 512);
        bf16x8 wl0 = *(const bf16x8*)(lb + (size_t)kt * 4096);
        bf16x8 wl1 = *(const bf16x8*)(lb + (size_t)kt * 4096 + 512);

        float f[8] = {xa.x, xa.y, xa.z, xa.w, xb.x, xb.y, xb.z, xb.w};
        unsigned uh[4], ul[4];
#pragma unroll
        for (int w = 0; w < 4; w++) {
            uh[w] = cvt_pk_bf16(f[2 * w], f[2 * w + 1]);
            float r0 = f[2 * w]     - __uint_as_float(uh[w] << 16);
            float r1 = f[2 * w + 1] - __uint_as_float(uh[w] & 0xffff0000u);
            ul[w] = cvt_pk_bf16(r0, r1);
        }
        bf16x8 xh = *(const bf16x8*)uh;
        bf16x8 xl = *(const bf16x8*)ul;

        acc0 = __builtin_amdgcn_mfma_f32_16x16x32_bf16(xh, wh0, acc0, 0, 0, 0);
        acc0 = __builtin_amdgcn_mfma_f32_16x16x32_bf16(xl, wh0, acc0, 0, 0, 0);
        acc0 = __builtin_amdgcn_mfma_f32_16x16x32_bf16(xh, wl0, acc0, 0, 0, 0);
        acc1 = __builtin_amdgcn_mfma_f32_16x16x32_bf16(xh, wh1, acc1, 0, 0, 0);
        acc1 = __builtin_amdgcn_mfma_f32_16x16x32_bf16(xl, wh1, acc1, 0, 0, 0);
        acc1 = __builtin_amdgcn_mfma_f32_16x16x32_bf16(xh, wl1, acc1, 0, 0, 0);
    }

    // ---- t1/t2: partial over this wave's 32 cols, butterfly over lr, LDS combine ----
    {
        float a10 = a1[(2 * wv) * 16 + lr], a11 = a1[(2 * wv + 1) * 16 + lr];
        float a20 = a2[(2 * wv) * 16 + lr], a21 = a2[(2 * wv + 1) * 16 + lr];
        float p1[4], p2[4];
#pragma unroll
        for (int r = 0; r < 4; r++) {
            p1[r] = acc0[r] * a10 + acc1[r] * a11;
            p2[r] = acc0[r] * a20 + acc1[r] * a21;
        }
#pragma unroll
        for (int off = 1; off < 16; off <<= 1) {
#pragma unroll
            for (int r = 0; r < 4; r++) {
                p1[r] += __shfl_xor(p1[r], off);
                p2[r] += __shfl_xor(p2[r], off);
            }
        }
        if (lr == 0) {
#pragma unroll
            for (int r = 0; r < 4; r++) {
                lds_t1[wv][lg * 4 + r] = p1[r];
                lds_t2[wv][lg * 4 + r] = p2[r];
            }
        }
        __syncthreads();
        if (tid < 16) {
            t1[row0 + tid] = lds_t1[0][tid] + lds_t1[1][tid] + lds_t1[2][tid] + lds_t1[3][tid];
            t2[row0 + tid] = lds_t2[0][tid] + lds_t2[1][tid] + lds_t2[2][tid] + lds_t2[3][tid];
        }
    }

    // ---- repack to B-fragment layout via intra-wave shuffles (no LDS) ----
    // C layout: lane lg*16+lr holds rows lg*4..+3 (regs), col t_o*16+lr.
    // Frag: lane klane*16+lr holds j=klane*8+jj; this block's rows are j-half (blk&1).
    // Packed u32 pair (rows lg*4..+1, lg*4+2..+3) of source group sg goes to
    // target klane with sg = 2*(klane&1)+{0,1}; active target lanes: klane>>1 == blk&1.
    {
        size_t jtg = (size_t)(blk >> 1);
        int srcbase = (2 * (lg & 1)) * 16 + lr;
        bool active = (lg >> 1) == (blk & 1);
#pragma unroll
        for (int t = 0; t < 2; t++) {
            f32x4 a = t == 0 ? acc0 : acc1;
            unsigned p0 = cvt_pk_bf16(a[0], a[1]);
            unsigned p1 = cvt_pk_bf16(a[2], a[3]);
            unsigned g0 = __shfl((int)p0, srcbase);
            unsigned g1 = __shfl((int)p1, srcbase);
            unsigned g2 = __shfl((int)p0, srcbase + 16);
            unsigned g3 = __shfl((int)p1, srcbase + 16);
            if (active) {
                uint4 v = {g0, g1, g2, g3};
                int t_o = 2 * wv + t;
                *(uint4*)(hb + (jtg * 8 + t_o) * 512 + l * 8) = v;
            }
        }
    }
}

// ---------------- Kernel B: fused masked-softmax attention + PV (MFMA) ----------------
// grid = B*N/16 = 512 blocks, 256 threads (4 waves).
// All waves share the same 16 i-rows; wave wv processes j-tiles jt ≡ wv (mod 4),
// each wave owns all 8 o-tiles. Cross-wave flash combine in LDS at the end.
__global__ void __launch_bounds__(256) k_attn(const int* __restrict__ adj,
                                              const float* __restrict__ t1g,
                                              const float* __restrict__ t2g,
                                              const unsigned short* __restrict__ hb,
                                              const int* __restrict__ d1p,
                                              const int* __restrict__ d2p,
                                              float* __restrict__ out) {
    __shared__ float accbuf[4][16][132];    // 33792 B, 2-way-free padding
    __shared__ float lds_m[4][16];
    __shared__ float lds_s[4][16];
    __shared__ float lds_inv[16];

    int blk = blockIdx.x;
    int b = blk >> 7;
    int i0 = (blk & 127) * 16;
    int tid = threadIdx.x;
    int wv = tid >> 6;
    int l = tid & 63;
    int lr = l & 15, lg = l >> 4;
    int d1 = d1p[0], d2 = d2p[0];

    float t1v = t1g[b * NN + i0 + lr];
    const int* adjRow = adj + ((size_t)(b * NN + i0 + lr)) * NN + lg * 8;
    const float* t2p = t2g + b * NN + lg * 8;
    const unsigned short* hbbase = hb + (size_t)b * 64 * 4096 + (size_t)l * 8;

    float m = NEGV, s = 0.f;
    f32x4 acc[8];
#pragma unroll
    for (int t = 0; t < 8; t++) acc[t] = (f32x4){0.f, 0.f, 0.f, 0.f};

#pragma unroll 2
    for (int jt = wv; jt < NN / 32; jt += 4) {
        int4 av0 = *(const int4*)(adjRow + jt * 32);
        int4 av1 = *(const int4*)(adjRow + jt * 32 + 4);
        float4 tb0 = *(const float4*)(t2p + jt * 32);
        float4 tb1 = *(const float4*)(t2p + jt * 32 + 4);
        bf16x8 hf[8];
#pragma unroll
        for (int t = 0; t < 8; t++)
            hf[t] = *(const bf16x8*)(hbbase + (size_t)jt * 4096 + t * 512);

        int ai[8] = {av0.x, av0.y, av0.z, av0.w, av1.x, av1.y, av1.z, av1.w};
        float tv[8] = {tb0.x, tb0.y, tb0.z, tb0.w, tb1.x, tb1.y, tb1.z, tb1.w};
        float att[8];
#pragma unroll
        for (int jj = 0; jj < 8; jj++) {
            float v = t1v + tv[jj];
            float e = fmaxf(v, ALPHAV * v);          // leaky relu (alpha<1)
            att[jj] = (ai[jj] == d1 || ai[jj] == d2) ? e : NEGV;
        }
        float mx = att[0];
#pragma unroll
        for (int jj = 1; jj < 8; jj++) mx = fmaxf(mx, att[jj]);
        mx = fmaxf(mx, __shfl_xor(mx, 16));
        mx = fmaxf(mx, __shfl_xor(mx, 32));

        if (__any(mx > m + 8.f)) {                   // T13 defer-max
            float mnew = fmaxf(m, mx);
            float scale = __expf(m - mnew);
            m = mnew;
            s *= scale;
            float scr[4];
#pragma unroll
            for (int r = 0; r < 4; r++) scr[r] = __shfl(scale, lg * 4 + r);
#pragma unroll
            for (int t = 0; t < 8; t++)
#pragma unroll
                for (int r = 0; r < 4; r++) acc[t][r] *= scr[r];
        }

        float p[8];
        float psum = 0.f;
#pragma unroll
        for (int jj = 0; jj < 8; jj++) {
            p[jj] = __expf(att[jj] - m);             // masked & m==NEGV -> exp(0)=1 (matches ref)
            psum += p[jj];
        }
        s += psum;

        unsigned u[4];
#pragma unroll
        for (int w = 0; w < 4; w++) u[w] = cvt_pk_bf16(p[2 * w], p[2 * w + 1]);
        bf16x8 pa = *(const bf16x8*)u;
#pragma unroll
        for (int t = 0; t < 8; t++)
            acc[t] = __builtin_amdgcn_mfma_f32_16x16x32_bf16(pa, hf[t], acc[t], 0, 0, 0);
    }

    // cross-wave flash combine
    s += __shfl_xor(s, 16);
    s += __shfl_xor(s, 32);
    if (l < 16) { lds_m[wv][lr] = m; lds_s[wv][lr] = s; }
    __syncthreads();

    float mt = fmaxf(fmaxf(lds_m[0][lr], lds_m[1][lr]),
                     fmaxf(lds_m[2][lr], lds_m[3][lr]));
    if (wv == 0 && l < 16) {
        float st = 0.f;
#pragma unroll
        for (int w = 0; w < 4; w++) st += lds_s[w][lr] * __expf(lds_m[w][lr] - mt);
        lds_inv[lr] = 1.0f / st;
    }
    float scale = __expf(m - mt);
    float scr[4];
#pragma unroll
    for (int r = 0; r < 4; r++) scr[r] = __shfl(scale, lg * 4 + r);
#pragma unroll
    for (int t = 0; t < 8; t++)
#pragma unroll
        for (int r = 0; r < 4; r++)
            accbuf[wv][lg * 4 + r][t * 16 + lr] = acc[t][r] * scr[r];
    __syncthreads();

#pragma unroll
    for (int e = 0; e < 8; e++) {
        int flat = tid + e * 256;
        int row = flat >> 7;
        int col = flat & 127;
        float sum = accbuf[0][row][col] + accbuf[1][row][col]
                  + accbuf[2][row][col] + accbuf[3][row][col];
        out[((size_t)b * NN + i0 + row) * FOUT + col] = sum * lds_inv[row];
    }
}

extern "C" void kernel_launch(void* const* d_in, const int* in_sizes, int n_in,
                              void* d_out, int out_size, void* d_ws, size_t ws_size,
                              hipStream_t stream) {
    const float* x  = (const float*)d_in[0];
    const float* W  = (const float*)d_in[1];
    const float* a1 = (const float*)d_in[2];
    const float* a2 = (const float*)d_in[3];
    const int* adj  = (const int*)d_in[4];
    // d_in[5] = adj_tree (unused by reference forward)
    const int* d1p  = (const int*)d_in[6];
    const int* d2p  = (const int*)d_in[7];
    float* out = (float*)d_out;

    char* ws = (char*)d_ws;
    unsigned short* hbuf = (unsigned short*)(ws);                       // 2 MB
    float* t1            = (float*)(ws + 2u * 1024 * 1024);             // 32 KB
    float* t2            = (float*)(ws + 2u * 1024 * 1024 + 32 * 1024); // 32 KB
    unsigned short* whi  = (unsigned short*)(ws + 2u * 1024 * 1024 + 64 * 1024);  // 128 KB
    unsigned short* wlo  = (unsigned short*)(ws + 2u * 1024 * 1024 + 192 * 1024); // 128 KB

    k_wrep<<<dim3(128), dim3(64), 0, stream>>>(W, whi, wlo);
    k_h<<<dim3(512), dim3(256), 0, stream>>>(x, whi, wlo, a1, a2, hbuf, t1, t2);
    k_attn<<<dim3(512), dim3(256), 0, stream>>>(adj, t1, t2, hbuf, d1p, d2p, out);
}